// Round 1
// baseline (604.759 us; speedup 1.0000x reference)
//
#include <hip/hip_runtime.h>

constexpr int S = 4096, M = 512, E = 16, CC = 128;
constexpr int H1 = 500, H2 = 500, H3 = 2000;

// select = x @ Wr^T + noise   (one wave per token)
__global__ void k_select(const float* __restrict__ x, const float* __restrict__ noise,
                         const float* __restrict__ Wr, float* __restrict__ sel) {
  int wid = (blockIdx.x * blockDim.x + threadIdx.x) >> 6;
  int lane = threadIdx.x & 63;
  if (wid >= S) return;
  const float* xr = x + (size_t)wid * M;
  float xv[8];
#pragma unroll
  for (int c = 0; c < 8; ++c) xv[c] = xr[lane + 64 * c];
  for (int e = 0; e < E; ++e) {
    const float* wr = Wr + (size_t)e * M;
    float acc = 0.f;
#pragma unroll
    for (int c = 0; c < 8; ++c) acc += xv[c] * wr[lane + 64 * c];
#pragma unroll
    for (int off = 32; off; off >>= 1) acc += __shfl_xor(acc, off);
    if (lane == 0) sel[wid * E + e] = acc + noise[wid * E + e];
  }
}

// top-2 per token + select0 (dispatch) output
__global__ void k_top2(const float* __restrict__ sel, int* __restrict__ i0, int* __restrict__ i1,
                       float* __restrict__ g0, float* __restrict__ g1, float* __restrict__ sel0) {
  int s = blockIdx.x * blockDim.x + threadIdx.x;
  if (s >= S) return;
  float v[E];
#pragma unroll
  for (int e = 0; e < E; ++e) v[e] = sel[s * E + e];
  int a0 = 0; float m0 = v[0];
#pragma unroll
  for (int e = 1; e < E; ++e) if (v[e] > m0) { m0 = v[e]; a0 = e; }
  int a1 = -1; float m1 = -3.4e38f;
#pragma unroll
  for (int e = 0; e < E; ++e) if (e != a0 && v[e] > m1) { m1 = v[e]; a1 = e; }
  i0[s] = a0; i1[s] = a1; g0[s] = m0; g1[s] = m1;
#pragma unroll
  for (int e = 0; e < E; ++e) {
    sel0[(size_t)s * (E * 2) + e * 2 + 0] = (e == a0 && m0 != 0.f) ? 1.f : 0.f;
    sel0[(size_t)s * (E * 2) + e * 2 + 1] = (e == a1 && m1 != 0.f) ? 1.f : 0.f;
  }
}

// balance_loss = (sum_s 0.5*(dp[i0]+dp[i1])) / 256, dp = colmean(select). Single block, deterministic.
__global__ void k_balance(const float* __restrict__ sel, const int* __restrict__ i0,
                          const int* __restrict__ i1, float* __restrict__ outb) {
  __shared__ double part[512];
  __shared__ float dpl[E];
  int t = threadIdx.x;
  int e = t & 15, r0 = t >> 4;
  double acc = 0.0;
  for (int s = r0; s < S; s += 32) acc += (double)sel[s * E + e];
  part[t] = acc;
  __syncthreads();
  for (int off = 256; off >= 16; off >>= 1) {
    if (t < off) part[t] += part[t + off];
    __syncthreads();
  }
  if (t < E) dpl[t] = (float)(part[t] / (double)S);
  __syncthreads();
  double acc2 = 0.0;
  for (int s = t; s < S; s += 512) acc2 += 0.5 * ((double)dpl[i0[s]] + (double)dpl[i1[s]]);
  part[t] = acc2;
  __syncthreads();
  for (int off = 256; off; off >>= 1) {
    if (t < off) part[t] += part[t + off];
    __syncthreads();
  }
  if (t == 0) outb[0] = (float)(part[0] / 256.0);
}

// expert_inputs[e,k,:] = sum of x rows routed to (e,k). Deterministic scan, no atomics.
__global__ void k_scatter(const float* __restrict__ x, const int* __restrict__ i0,
                          const int* __restrict__ i1, const float* __restrict__ g0,
                          const float* __restrict__ g1, float* __restrict__ ei) {
  __shared__ int rsi[256];
  __shared__ float rsg[256];
  int b = blockIdx.x;                       // E*K*4 = 128 blocks
  int chunk = b & 3, k = (b >> 2) & 1, e = b >> 3;
  const int* route = k ? i1 : i0;
  const float* gg = k ? g1 : g0;
  int t = threadIdx.x;                      // 128 threads
  int d = chunk * 128 + t;
  float acc = 0.f;
  for (int s0 = 0; s0 < S; s0 += 256) {
    rsi[t] = route[s0 + t];       rsi[t + 128] = route[s0 + t + 128];
    rsg[t] = gg[s0 + t];          rsg[t + 128] = gg[s0 + t + 128];
    __syncthreads();
    for (int q = 0; q < 256; ++q) {
      if (rsi[q] == e && rsg[q] != 0.f) acc += x[(size_t)(s0 + q) * M + d];
    }
    __syncthreads();
  }
  ei[(e * 2 + k) * M + d] = acc;
}

// generic MLP layer: wave per (e,h) output neuron, both k rows at once
template <int DIN, int HOUT, bool RELU>
__global__ void k_layer(const float* __restrict__ in, const float* __restrict__ W,
                        const float* __restrict__ bias, float* __restrict__ out) {
  int w = (blockIdx.x * blockDim.x + threadIdx.x) >> 6;
  int lane = threadIdx.x & 63;
  if (w >= E * HOUT) return;
  int e = w / HOUT, h = w - e * HOUT;
  const float* wr = W + ((size_t)e * HOUT + h) * DIN;
  const float* in0 = in + (size_t)(e * 2 + 0) * DIN;
  const float* in1 = in + (size_t)(e * 2 + 1) * DIN;
  float a0 = 0.f, a1 = 0.f;
  for (int m = lane; m < DIN; m += 64) {
    float wv = wr[m];
    a0 += wv * in0[m];
    a1 += wv * in1[m];
  }
#pragma unroll
  for (int off = 32; off; off >>= 1) {
    a0 += __shfl_xor(a0, off);
    a1 += __shfl_xor(a1, off);
  }
  if (lane == 0) {
    float bb = bias[e * HOUT + h];
    float o0 = a0 + bb, o1 = a1 + bb;
    if (RELU) { o0 = fmaxf(o0, 0.f); o1 = fmaxf(o1, 0.f); }
    out[(size_t)(e * 2 + 0) * HOUT + h] = o0;
    out[(size_t)(e * 2 + 1) * HOUT + h] = o1;
  }
}

// output[s,d] = g0*eout[i0,0,d] + g1*eout[i1,1,d]
__global__ void k_output(const float* __restrict__ eo, const int* __restrict__ i0,
                         const int* __restrict__ i1, const float* __restrict__ g0,
                         const float* __restrict__ g1, float* __restrict__ out) {
  int idx = blockIdx.x * blockDim.x + threadIdx.x;
  if (idx >= S * CC) return;
  int s = idx >> 7, d = idx & (CC - 1);
  out[idx] = g0[s] * eo[(i0[s] * 2 + 0) * CC + d] + g1[s] * eo[(i1[s] * 2 + 1) * CC + d];
}

// T rows (source then target, zero pad) + row sq-norms
__global__ void k_buildT(const float* __restrict__ eo, const int* __restrict__ idx1,
                         const int* __restrict__ idx2, const int* __restrict__ i0,
                         const int* __restrict__ i1, const float* __restrict__ g0,
                         const float* __restrict__ g1, float* __restrict__ T,
                         float* __restrict__ sq, int ns, int n) {
  int r = blockIdx.x, d = threadIdx.x;
  float v = 0.f;
  if (r < ns)      { int t = idx1[r];      v = g0[t] * eo[(i0[t] * 2 + 0) * CC + d]; }
  else if (r < n)  { int t = idx2[r - ns]; v = g1[t] * eo[(i1[t] * 2 + 1) * CC + d]; }
  T[(size_t)r * CC + d] = v;
  __shared__ float red[128];
  red[d] = v * v;
  __syncthreads();
  for (int off = 64; off; off >>= 1) { if (d < off) red[d] += red[d + off]; __syncthreads(); }
  if (d == 0) sq[r] = red[0];
}

// column-sum partials (for analytic sum(d2))
__global__ void k_colsum(const float* __restrict__ T, double* __restrict__ part, int n) {
  int d = threadIdx.x, b = blockIdx.x;
  int r0 = b * 128, r1 = min(r0 + 128, n);
  double acc = 0.0;
  for (int r = r0; r < r1; ++r) acc += (double)T[(size_t)r * CC + d];
  part[b * 128 + d] = acc;
}

// bw = (2n*sum(sq) - 2*||colsum||^2)/(n^2-n)/4 ; store cl[l] = 1/(bw*2^l)
__global__ void k_prep(const double* __restrict__ part, const float* __restrict__ sq,
                       float* __restrict__ cl, int n, int nblk) {
  __shared__ double red[128];
  __shared__ double csum2s;
  int d = threadIdx.x;
  double cs = 0.0;
  for (int b = 0; b < nblk; ++b) cs += part[b * 128 + d];
  red[d] = cs * cs;
  __syncthreads();
  for (int off = 64; off; off >>= 1) { if (d < off) red[d] += red[d + off]; __syncthreads(); }
  if (d == 0) csum2s = red[0];
  __syncthreads();
  double ss = 0.0;
  for (int r = d; r < n; r += 128) ss += (double)sq[r];
  red[d] = ss;
  __syncthreads();
  for (int off = 64; off; off >>= 1) { if (d < off) red[d] += red[d + off]; __syncthreads(); }
  if (d == 0) {
    double ssq = red[0];
    double nn = (double)n;
    double bwsum = 2.0 * nn * ssq - 2.0 * csum2s;
    double bw = bwsum / (nn * nn - nn) / 4.0;
#pragma unroll
    for (int l = 0; l < 5; ++l) cl[l] = (float)(1.0 / (bw * (double)(1 << l)));
  }
}

// fused Gram + d2 + 5-scale exp + signed sum over 64x64 pair tiles (upper triangle, x2 off-diag)
__global__ __launch_bounds__(256) void k_mmd(const float* __restrict__ T, const float* __restrict__ sq,
                      const float* __restrict__ cl, double* __restrict__ bsum,
                      int ns, int n, int nt) {
  int bi = blockIdx.x, bj = blockIdx.y;
  int tid = threadIdx.x;
  if (bj < bi) { if (tid == 0) bsum[(size_t)bi * nt + bj] = 0.0; return; }
  __shared__ float Ta[64][132];
  __shared__ float Tb[64][132];
  __shared__ float sqa[64], sqb[64], sga[64], sgb[64];
  __shared__ float rsum[256];
  const int ib = bi * 64, jb = bj * 64;
  // load tiles with float4-column rotation swizzle: col' = (c4 + row/4) & 31
  for (int idx = tid; idx < 64 * 32; idx += 256) {
    int r = idx >> 5, c4 = idx & 31;
    int cs = ((c4 + (r >> 2)) & 31) * 4;
    *(float4*)&Ta[r][cs] = *(const float4*)&T[((size_t)(ib + r)) * CC + c4 * 4];
    *(float4*)&Tb[r][cs] = *(const float4*)&T[((size_t)(jb + r)) * CC + c4 * 4];
  }
  if (tid < 64) {
    int i = ib + tid, j = jb + tid;
    sqa[tid] = sq[i];
    sqb[tid] = sq[j];
    sga[tid] = (i < ns) ? 1.f : (i < n ? -1.f : 0.f);
    sgb[tid] = (j < ns) ? 1.f : (j < n ? -1.f : 0.f);
  }
  __syncthreads();
  int ti = tid & 15, tj = tid >> 4;
  float acc[4][4];
#pragma unroll
  for (int r = 0; r < 4; ++r)
#pragma unroll
    for (int c = 0; c < 4; ++c) acc[r][c] = 0.f;
#pragma unroll 4
  for (int d4 = 0; d4 < 32; ++d4) {
    int ca = ((d4 + ti) & 31) * 4;
    int cb = ((d4 + tj) & 31) * 4;
    float4 av[4], bv[4];
#pragma unroll
    for (int r = 0; r < 4; ++r) av[r] = *(const float4*)&Ta[ti * 4 + r][ca];
#pragma unroll
    for (int c = 0; c < 4; ++c) bv[c] = *(const float4*)&Tb[tj * 4 + c][cb];
#pragma unroll
    for (int r = 0; r < 4; ++r)
#pragma unroll
      for (int c = 0; c < 4; ++c)
        acc[r][c] += av[r].x * bv[c].x + av[r].y * bv[c].y + av[r].z * bv[c].z + av[r].w * bv[c].w;
  }
  float c0 = cl[0], c1 = cl[1], c2 = cl[2], c3 = cl[3], c4v = cl[4];
  float tsum = 0.f;
#pragma unroll
  for (int r = 0; r < 4; ++r) {
    float sa = sqa[ti * 4 + r], wa = sga[ti * 4 + r];
#pragma unroll
    for (int c = 0; c < 4; ++c) {
      float d2 = sa + sqb[tj * 4 + c] - 2.f * acc[r][c];
      float w = wa * sgb[tj * 4 + c];
      float k5 = __expf(-d2 * c0) + __expf(-d2 * c1) + __expf(-d2 * c2) +
                 __expf(-d2 * c3) + __expf(-d2 * c4v);
      tsum += w * k5;
    }
  }
  rsum[tid] = tsum;
  __syncthreads();
  for (int off = 128; off; off >>= 1) {
    if (tid < off) rsum[tid] += rsum[tid + off];
    __syncthreads();
  }
  if (tid == 0) bsum[(size_t)bi * nt + bj] = (double)rsum[0] * ((bi == bj) ? 1.0 : 2.0);
}

__global__ void k_final(const double* __restrict__ bsum, int nb, int ns, float* __restrict__ outp) {
  __shared__ double red[256];
  int t = threadIdx.x;
  double acc = 0.0;
  for (int i = t; i < nb; i += 256) acc += bsum[i];
  red[t] = acc;
  __syncthreads();
  for (int off = 128; off; off >>= 1) { if (t < off) red[t] += red[t + off]; __syncthreads(); }
  if (t == 0) outp[0] = (float)(-red[0] / ((double)ns * (double)ns));
}

extern "C" void kernel_launch(void* const* d_in, const int* in_sizes, int n_in,
                              void* d_out, int out_size, void* d_ws, size_t ws_size,
                              hipStream_t stream) {
  const float* x  = (const float*)d_in[0];
  const float* noise = (const float*)d_in[1];
  const float* Wr = (const float*)d_in[2];
  const float* W1 = (const float*)d_in[3];
  const float* b1 = (const float*)d_in[4];
  const float* W2 = (const float*)d_in[5];
  const float* b2 = (const float*)d_in[6];
  const float* W3 = (const float*)d_in[7];
  const float* b3 = (const float*)d_in[8];
  const float* W4 = (const float*)d_in[9];
  const float* b4 = (const float*)d_in[10];
  const int* idx1 = (const int*)d_in[11];
  const int* idx2 = (const int*)d_in[12];
  int ns = in_sizes[11];          // SAMPLE (npairs==1)
  int n = 2 * ns;
  int npad = (n + 63) & ~63;
  int nt = npad / 64;
  int nblk = (n + 127) / 128;

  char* wp = (char*)d_ws;
  size_t off = 0;
  auto alloc = [&](size_t bytes) -> void* {
    void* p = wp + off;
    off += (bytes + 255) & ~(size_t)255;
    return p;
  };
  float* sel = (float*)alloc((size_t)S * E * 4);
  int*   i0  = (int*)alloc((size_t)S * 4);
  int*   i1  = (int*)alloc((size_t)S * 4);
  float* g0  = (float*)alloc((size_t)S * 4);
  float* g1  = (float*)alloc((size_t)S * 4);
  float* ei  = (float*)alloc((size_t)E * 2 * M * 4);
  float* h1  = (float*)alloc((size_t)E * 2 * H1 * 4);
  float* h2  = (float*)alloc((size_t)E * 2 * H2 * 4);
  float* h3  = (float*)alloc((size_t)E * 2 * H3 * 4);
  float* eo  = (float*)alloc((size_t)E * 2 * CC * 4);
  float* T   = (float*)alloc((size_t)npad * CC * 4);
  float* sq  = (float*)alloc((size_t)npad * 4);
  float* cl  = (float*)alloc(8 * 4);
  double* cspart = (double*)alloc((size_t)nblk * 128 * 8);
  double* bsum   = (double*)alloc((size_t)nt * nt * 8);
  (void)ws_size; (void)n_in; (void)out_size;

  float* out      = (float*)d_out;
  float* out_sel0 = out + (size_t)S * CC;
  float* out_bal  = out + (size_t)S * CC + (size_t)S * E * 2;
  float* out_dist = out_bal + 1;

  k_select<<<S / 4, 256, 0, stream>>>(x, noise, Wr, sel);
  k_top2<<<S / 256, 256, 0, stream>>>(sel, i0, i1, g0, g1, out_sel0);
  k_balance<<<1, 512, 0, stream>>>(sel, i0, i1, out_bal);
  k_scatter<<<E * 2 * 4, 128, 0, stream>>>(x, i0, i1, g0, g1, ei);
  k_layer<M, H1, true><<<(E * H1 + 3) / 4, 256, 0, stream>>>(ei, W1, b1, h1);
  k_layer<H1, H2, true><<<(E * H2 + 3) / 4, 256, 0, stream>>>(h1, W2, b2, h2);
  k_layer<H2, H3, true><<<(E * H3 + 3) / 4, 256, 0, stream>>>(h2, W3, b3, h3);
  k_layer<H3, CC, false><<<(E * CC + 3) / 4, 256, 0, stream>>>(h3, W4, b4, eo);
  k_output<<<(S * CC) / 256, 256, 0, stream>>>(eo, i0, i1, g0, g1, out);
  k_buildT<<<npad, 128, 0, stream>>>(eo, idx1, idx2, i0, i1, g0, g1, T, sq, ns, n);
  k_colsum<<<nblk, 128, 0, stream>>>(T, cspart, n);
  k_prep<<<1, 128, 0, stream>>>(cspart, sq, cl, n, nblk);
  k_mmd<<<dim3(nt, nt), 256, 0, stream>>>(T, sq, cl, bsum, ns, n, nt);
  k_final<<<1, 256, 0, stream>>>(bsum, nt * nt, ns, out_dist);
}

// Round 2
// 350.754 us; speedup vs baseline: 1.7242x; 1.7242x over previous
//
#include <hip/hip_runtime.h>

constexpr int S = 4096, M = 512, E = 16, CC = 128;
constexpr int H1 = 500, H2 = 500, H3 = 2000;
constexpr int NSEG = 16;

// select = x @ Wr^T + noise   (one wave per token)
__global__ void k_select(const float* __restrict__ x, const float* __restrict__ noise,
                         const float* __restrict__ Wr, float* __restrict__ sel) {
  int wid = (blockIdx.x * blockDim.x + threadIdx.x) >> 6;
  int lane = threadIdx.x & 63;
  if (wid >= S) return;
  const float* xr = x + (size_t)wid * M;
  float xv[8];
#pragma unroll
  for (int c = 0; c < 8; ++c) xv[c] = xr[lane + 64 * c];
  for (int e = 0; e < E; ++e) {
    const float* wr = Wr + (size_t)e * M;
    float acc = 0.f;
#pragma unroll
    for (int c = 0; c < 8; ++c) acc += xv[c] * wr[lane + 64 * c];
#pragma unroll
    for (int off = 32; off; off >>= 1) acc += __shfl_xor(acc, off);
    if (lane == 0) sel[wid * E + e] = acc + noise[wid * E + e];
  }
}

// top-2 per token + select0 (dispatch) output
__global__ void k_top2(const float* __restrict__ sel, int* __restrict__ i0, int* __restrict__ i1,
                       float* __restrict__ g0, float* __restrict__ g1, float* __restrict__ sel0) {
  int s = blockIdx.x * blockDim.x + threadIdx.x;
  if (s >= S) return;
  float v[E];
#pragma unroll
  for (int e = 0; e < E; ++e) v[e] = sel[s * E + e];
  int a0 = 0; float m0 = v[0];
#pragma unroll
  for (int e = 1; e < E; ++e) if (v[e] > m0) { m0 = v[e]; a0 = e; }
  int a1 = -1; float m1 = -3.4e38f;
#pragma unroll
  for (int e = 0; e < E; ++e) if (e != a0 && v[e] > m1) { m1 = v[e]; a1 = e; }
  i0[s] = a0; i1[s] = a1; g0[s] = m0; g1[s] = m1;
#pragma unroll
  for (int e = 0; e < E; ++e) {
    sel0[(size_t)s * (E * 2) + e * 2 + 0] = (e == a0 && m0 != 0.f) ? 1.f : 0.f;
    sel0[(size_t)s * (E * 2) + e * 2 + 1] = (e == a1 && m1 != 0.f) ? 1.f : 0.f;
  }
}

// balance_loss = (sum_s 0.5*(dp[i0]+dp[i1])) / 256, dp = colmean(select). Single block, deterministic.
__global__ void k_balance(const float* __restrict__ sel, const int* __restrict__ i0,
                          const int* __restrict__ i1, float* __restrict__ outb) {
  __shared__ double part[512];
  __shared__ float dpl[E];
  int t = threadIdx.x;
  int e = t & 15, r0 = t >> 4;
  double acc = 0.0;
  for (int s = r0; s < S; s += 32) acc += (double)sel[s * E + e];
  part[t] = acc;
  __syncthreads();
  for (int off = 256; off >= 16; off >>= 1) {
    if (t < off) part[t] += part[t + off];
    __syncthreads();
  }
  if (t < E) dpl[t] = (float)(part[t] / (double)S);
  __syncthreads();
  double acc2 = 0.0;
  for (int s = t; s < S; s += 512) acc2 += 0.5 * ((double)dpl[i0[s]] + (double)dpl[i1[s]]);
  part[t] = acc2;
  __syncthreads();
  for (int off = 256; off; off >>= 1) {
    if (t < off) part[t] += part[t + off];
    __syncthreads();
  }
  if (t == 0) outb[0] = (float)(part[0] / 256.0);
}

// expert_inputs partials: block = ((e*2+k)*4 + chunk)*NSEG + seg; scans 256 tokens.
__global__ void k_scatter_part(const float* __restrict__ x, const int* __restrict__ i0,
                               const int* __restrict__ i1, const float* __restrict__ g0,
                               const float* __restrict__ g1, float* __restrict__ part) {
  __shared__ int rsi[256];
  __shared__ float rsg[256];
  int b = blockIdx.x;
  int seg = b & (NSEG - 1);
  int rest = b >> 4;
  int chunk = rest & 3;
  int ek = rest >> 2;            // 0..31
  int k = ek & 1, e = ek >> 1;
  const int* route = k ? i1 : i0;
  const float* gg = k ? g1 : g0;
  int t = threadIdx.x;           // 128
  int d = chunk * 128 + t;
  int s0 = seg * (S / NSEG);     // 256-token segment
  rsi[t] = route[s0 + t];        rsi[t + 128] = route[s0 + t + 128];
  rsg[t] = gg[s0 + t];           rsg[t + 128] = gg[s0 + t + 128];
  __syncthreads();
  float acc = 0.f;
  for (int q = 0; q < 256; ++q) {
    if (rsi[q] == e && rsg[q] != 0.f) acc += x[(size_t)(s0 + q) * M + d];
  }
  part[(size_t)seg * (E * 2 * M) + (size_t)ek * M + d] = acc;
}

// sum the NSEG partials in fixed order
__global__ void k_scatter_red(const float* __restrict__ part, float* __restrict__ ei) {
  int idx = blockIdx.x * blockDim.x + threadIdx.x;   // E*2*M = 16384
  float acc = 0.f;
#pragma unroll
  for (int sg = 0; sg < NSEG; ++sg) acc += part[(size_t)sg * (E * 2 * M) + idx];
  ei[idx] = acc;
}

// generic MLP layer: wave per (e,h) output neuron, both k rows at once
template <int DIN, int HOUT, bool RELU>
__global__ void k_layer(const float* __restrict__ in, const float* __restrict__ W,
                        const float* __restrict__ bias, float* __restrict__ out) {
  int w = (blockIdx.x * blockDim.x + threadIdx.x) >> 6;
  int lane = threadIdx.x & 63;
  if (w >= E * HOUT) return;
  int e = w / HOUT, h = w - e * HOUT;
  const float* wr = W + ((size_t)e * HOUT + h) * DIN;
  const float* in0 = in + (size_t)(e * 2 + 0) * DIN;
  const float* in1 = in + (size_t)(e * 2 + 1) * DIN;
  float a0 = 0.f, a1 = 0.f;
  for (int m = lane; m < DIN; m += 64) {
    float wv = wr[m];
    a0 += wv * in0[m];
    a1 += wv * in1[m];
  }
#pragma unroll
  for (int off = 32; off; off >>= 1) {
    a0 += __shfl_xor(a0, off);
    a1 += __shfl_xor(a1, off);
  }
  if (lane == 0) {
    float bb = bias[e * HOUT + h];
    float o0 = a0 + bb, o1 = a1 + bb;
    if (RELU) { o0 = fmaxf(o0, 0.f); o1 = fmaxf(o1, 0.f); }
    out[(size_t)(e * 2 + 0) * HOUT + h] = o0;
    out[(size_t)(e * 2 + 1) * HOUT + h] = o1;
  }
}

// output[s,d] = g0*eout[i0,0,d] + g1*eout[i1,1,d]
__global__ void k_output(const float* __restrict__ eo, const int* __restrict__ i0,
                         const int* __restrict__ i1, const float* __restrict__ g0,
                         const float* __restrict__ g1, float* __restrict__ out) {
  int idx = blockIdx.x * blockDim.x + threadIdx.x;
  if (idx >= S * CC) return;
  int s = idx >> 7, d = idx & (CC - 1);
  out[idx] = g0[s] * eo[(i0[s] * 2 + 0) * CC + d] + g1[s] * eo[(i1[s] * 2 + 1) * CC + d];
}

// T rows (source then target, zero pad) + row sq-norms
__global__ void k_buildT(const float* __restrict__ eo, const int* __restrict__ idx1,
                         const int* __restrict__ idx2, const int* __restrict__ i0,
                         const int* __restrict__ i1, const float* __restrict__ g0,
                         const float* __restrict__ g1, float* __restrict__ T,
                         float* __restrict__ sq, int ns, int n) {
  int r = blockIdx.x, d = threadIdx.x;
  float v = 0.f;
  if (r < ns)      { int t = idx1[r];      v = g0[t] * eo[(i0[t] * 2 + 0) * CC + d]; }
  else if (r < n)  { int t = idx2[r - ns]; v = g1[t] * eo[(i1[t] * 2 + 1) * CC + d]; }
  T[(size_t)r * CC + d] = v;
  __shared__ float red[128];
  red[d] = v * v;
  __syncthreads();
  for (int off = 64; off; off >>= 1) { if (d < off) red[d] += red[d + off]; __syncthreads(); }
  if (d == 0) sq[r] = red[0];
}

// column-sum partials (for analytic sum(d2))
__global__ void k_colsum(const float* __restrict__ T, double* __restrict__ part, int n) {
  int d = threadIdx.x, b = blockIdx.x;
  int r0 = b * 128, r1 = min(r0 + 128, n);
  double acc = 0.0;
  for (int r = r0; r < r1; ++r) acc += (double)T[(size_t)r * CC + d];
  part[b * 128 + d] = acc;
}

// bw = (2n*sum(sq) - 2*||colsum||^2)/(n^2-n)/4 ; store cl[l] = 1/(bw*2^l)
__global__ void k_prep(const double* __restrict__ part, const float* __restrict__ sq,
                       float* __restrict__ cl, int n, int nblk) {
  __shared__ double red[128];
  __shared__ double csum2s;
  int d = threadIdx.x;
  double cs = 0.0;
  for (int b = 0; b < nblk; ++b) cs += part[b * 128 + d];
  red[d] = cs * cs;
  __syncthreads();
  for (int off = 64; off; off >>= 1) { if (d < off) red[d] += red[d + off]; __syncthreads(); }
  if (d == 0) csum2s = red[0];
  __syncthreads();
  double ss = 0.0;
  for (int r = d; r < n; r += 128) ss += (double)sq[r];
  red[d] = ss;
  __syncthreads();
  for (int off = 64; off; off >>= 1) { if (d < off) red[d] += red[d + off]; __syncthreads(); }
  if (d == 0) {
    double ssq = red[0];
    double nn = (double)n;
    double bwsum = 2.0 * nn * ssq - 2.0 * csum2s;
    double bw = bwsum / (nn * nn - nn) / 4.0;
#pragma unroll
    for (int l = 0; l < 5; ++l) cl[l] = (float)(1.0 / (bw * (double)(1 << l)));
  }
}

// fused Gram + d2 + 5-scale exp + signed sum over 64x64 pair tiles (upper triangle, x2 off-diag)
__global__ __launch_bounds__(256) void k_mmd(const float* __restrict__ T, const float* __restrict__ sq,
                      const float* __restrict__ cl, double* __restrict__ bsum,
                      int ns, int n, int nt) {
  int bi = blockIdx.x, bj = blockIdx.y;
  int tid = threadIdx.x;
  if (bj < bi) { if (tid == 0) bsum[(size_t)bi * nt + bj] = 0.0; return; }
  __shared__ float Ta[64][132];
  __shared__ float Tb[64][132];
  __shared__ float sqa[64], sqb[64], sga[64], sgb[64];
  __shared__ float rsum[256];
  const int ib = bi * 64, jb = bj * 64;
  for (int idx = tid; idx < 64 * 32; idx += 256) {
    int r = idx >> 5, c4 = idx & 31;
    int cs = ((c4 + (r >> 2)) & 31) * 4;
    *(float4*)&Ta[r][cs] = *(const float4*)&T[((size_t)(ib + r)) * CC + c4 * 4];
    *(float4*)&Tb[r][cs] = *(const float4*)&T[((size_t)(jb + r)) * CC + c4 * 4];
  }
  if (tid < 64) {
    int i = ib + tid, j = jb + tid;
    sqa[tid] = sq[i];
    sqb[tid] = sq[j];
    sga[tid] = (i < ns) ? 1.f : (i < n ? -1.f : 0.f);
    sgb[tid] = (j < ns) ? 1.f : (j < n ? -1.f : 0.f);
  }
  __syncthreads();
  int ti = tid & 15, tj = tid >> 4;
  float acc[4][4];
#pragma unroll
  for (int r = 0; r < 4; ++r)
#pragma unroll
    for (int c = 0; c < 4; ++c) acc[r][c] = 0.f;
#pragma unroll 4
  for (int d4 = 0; d4 < 32; ++d4) {
    int ca = ((d4 + ti) & 31) * 4;
    int cb = ((d4 + tj) & 31) * 4;
    float4 av[4], bv[4];
#pragma unroll
    for (int r = 0; r < 4; ++r) av[r] = *(const float4*)&Ta[ti * 4 + r][ca];
#pragma unroll
    for (int c = 0; c < 4; ++c) bv[c] = *(const float4*)&Tb[tj * 4 + c][cb];
#pragma unroll
    for (int r = 0; r < 4; ++r)
#pragma unroll
      for (int c = 0; c < 4; ++c)
        acc[r][c] += av[r].x * bv[c].x + av[r].y * bv[c].y + av[r].z * bv[c].z + av[r].w * bv[c].w;
  }
  float c0 = cl[0], c1 = cl[1], c2 = cl[2], c3 = cl[3], c4v = cl[4];
  float tsum = 0.f;
#pragma unroll
  for (int r = 0; r < 4; ++r) {
    float sa = sqa[ti * 4 + r], wa = sga[ti * 4 + r];
#pragma unroll
    for (int c = 0; c < 4; ++c) {
      float d2 = sa + sqb[tj * 4 + c] - 2.f * acc[r][c];
      float w = wa * sgb[tj * 4 + c];
      float k5 = __expf(-d2 * c0) + __expf(-d2 * c1) + __expf(-d2 * c2) +
                 __expf(-d2 * c3) + __expf(-d2 * c4v);
      tsum += w * k5;
    }
  }
  rsum[tid] = tsum;
  __syncthreads();
  for (int off = 128; off; off >>= 1) {
    if (tid < off) rsum[tid] += rsum[tid + off];
    __syncthreads();
  }
  if (tid == 0) bsum[(size_t)bi * nt + bj] = (double)rsum[0] * ((bi == bj) ? 1.0 : 2.0);
}

__global__ void k_final(const double* __restrict__ bsum, int nb, int ns, float* __restrict__ outp) {
  __shared__ double red[256];
  int t = threadIdx.x;
  double acc = 0.0;
  for (int i = t; i < nb; i += 256) acc += bsum[i];
  red[t] = acc;
  __syncthreads();
  for (int off = 128; off; off >>= 1) { if (t < off) red[t] += red[t + off]; __syncthreads(); }
  if (t == 0) outp[0] = (float)(-red[0] / ((double)ns * (double)ns));
}

extern "C" void kernel_launch(void* const* d_in, const int* in_sizes, int n_in,
                              void* d_out, int out_size, void* d_ws, size_t ws_size,
                              hipStream_t stream) {
  const float* x  = (const float*)d_in[0];
  const float* noise = (const float*)d_in[1];
  const float* Wr = (const float*)d_in[2];
  const float* W1 = (const float*)d_in[3];
  const float* b1 = (const float*)d_in[4];
  const float* W2 = (const float*)d_in[5];
  const float* b2 = (const float*)d_in[6];
  const float* W3 = (const float*)d_in[7];
  const float* b3 = (const float*)d_in[8];
  const float* W4 = (const float*)d_in[9];
  const float* b4 = (const float*)d_in[10];
  const int* idx1 = (const int*)d_in[11];
  const int* idx2 = (const int*)d_in[12];
  int ns = in_sizes[11];          // SAMPLE (npairs==1)
  int n = 2 * ns;
  int npad = (n + 63) & ~63;
  int nt = npad / 64;
  int nblk = (n + 127) / 128;

  char* wp = (char*)d_ws;
  size_t off = 0;
  auto alloc = [&](size_t bytes) -> void* {
    void* p = wp + off;
    off += (bytes + 255) & ~(size_t)255;
    return p;
  };
  float* sel = (float*)alloc((size_t)S * E * 4);
  int*   i0  = (int*)alloc((size_t)S * 4);
  int*   i1  = (int*)alloc((size_t)S * 4);
  float* g0  = (float*)alloc((size_t)S * 4);
  float* g1  = (float*)alloc((size_t)S * 4);
  float* ei  = (float*)alloc((size_t)E * 2 * M * 4);
  float* eipart = (float*)alloc((size_t)NSEG * E * 2 * M * 4);
  float* h1  = (float*)alloc((size_t)E * 2 * H1 * 4);
  float* h2  = (float*)alloc((size_t)E * 2 * H2 * 4);
  float* h3  = (float*)alloc((size_t)E * 2 * H3 * 4);
  float* eo  = (float*)alloc((size_t)E * 2 * CC * 4);
  float* T   = (float*)alloc((size_t)npad * CC * 4);
  float* sq  = (float*)alloc((size_t)npad * 4);
  float* cl  = (float*)alloc(8 * 4);
  double* cspart = (double*)alloc((size_t)nblk * 128 * 8);
  double* bsum   = (double*)alloc((size_t)nt * nt * 8);
  (void)ws_size; (void)n_in; (void)out_size;

  float* out      = (float*)d_out;
  float* out_sel0 = out + (size_t)S * CC;
  float* out_bal  = out + (size_t)S * CC + (size_t)S * E * 2;
  float* out_dist = out_bal + 1;

  k_select<<<S / 4, 256, 0, stream>>>(x, noise, Wr, sel);
  k_top2<<<S / 256, 256, 0, stream>>>(sel, i0, i1, g0, g1, out_sel0);
  k_balance<<<1, 512, 0, stream>>>(sel, i0, i1, out_bal);
  k_scatter_part<<<E * 2 * 4 * NSEG, 128, 0, stream>>>(x, i0, i1, g0, g1, eipart);
  k_scatter_red<<<(E * 2 * M) / 256, 256, 0, stream>>>(eipart, ei);
  k_layer<M, H1, true><<<(E * H1 + 3) / 4, 256, 0, stream>>>(ei, W1, b1, h1);
  k_layer<H1, H2, true><<<(E * H2 + 3) / 4, 256, 0, stream>>>(h1, W2, b2, h2);
  k_layer<H2, H3, true><<<(E * H3 + 3) / 4, 256, 0, stream>>>(h2, W3, b3, h3);
  k_layer<H3, CC, false><<<(E * CC + 3) / 4, 256, 0, stream>>>(h3, W4, b4, eo);
  k_output<<<(S * CC) / 256, 256, 0, stream>>>(eo, i0, i1, g0, g1, out);
  k_buildT<<<npad, 128, 0, stream>>>(eo, idx1, idx2, i0, i1, g0, g1, T, sq, ns, n);
  k_colsum<<<nblk, 128, 0, stream>>>(T, cspart, n);
  k_prep<<<1, 128, 0, stream>>>(cspart, sq, cl, n, nblk);
  k_mmd<<<dim3(nt, nt), 256, 0, stream>>>(T, sq, cl, bsum, ns, n, nt);
  k_final<<<1, 256, 0, stream>>>(bsum, nt * nt, ns, out_dist);
}

// Round 3
// 241.794 us; speedup vs baseline: 2.5011x; 1.4506x over previous
//
#include <hip/hip_runtime.h>

constexpr int S = 4096, M = 512, E = 16, CC = 128;
constexpr int H1 = 500, H2 = 500, H3 = 2000;
constexpr int NSEG = 16;

typedef short short8 __attribute__((ext_vector_type(8)));
typedef float f32x16 __attribute__((ext_vector_type(16)));

// select = x @ Wr^T + noise   (one wave per token)
__global__ void k_select(const float* __restrict__ x, const float* __restrict__ noise,
                         const float* __restrict__ Wr, float* __restrict__ sel) {
  int wid = (blockIdx.x * blockDim.x + threadIdx.x) >> 6;
  int lane = threadIdx.x & 63;
  if (wid >= S) return;
  const float* xr = x + (size_t)wid * M;
  float xv[8];
#pragma unroll
  for (int c = 0; c < 8; ++c) xv[c] = xr[lane + 64 * c];
  for (int e = 0; e < E; ++e) {
    const float* wr = Wr + (size_t)e * M;
    float acc = 0.f;
#pragma unroll
    for (int c = 0; c < 8; ++c) acc += xv[c] * wr[lane + 64 * c];
#pragma unroll
    for (int off = 32; off; off >>= 1) acc += __shfl_xor(acc, off);
    if (lane == 0) sel[wid * E + e] = acc + noise[wid * E + e];
  }
}

// top-2 per token + select0 (dispatch) output
__global__ void k_top2(const float* __restrict__ sel, int* __restrict__ i0, int* __restrict__ i1,
                       float* __restrict__ g0, float* __restrict__ g1, float* __restrict__ sel0) {
  int s = blockIdx.x * blockDim.x + threadIdx.x;
  if (s >= S) return;
  float v[E];
#pragma unroll
  for (int e = 0; e < E; ++e) v[e] = sel[s * E + e];
  int a0 = 0; float m0 = v[0];
#pragma unroll
  for (int e = 1; e < E; ++e) if (v[e] > m0) { m0 = v[e]; a0 = e; }
  int a1 = -1; float m1 = -3.4e38f;
#pragma unroll
  for (int e = 0; e < E; ++e) if (e != a0 && v[e] > m1) { m1 = v[e]; a1 = e; }
  i0[s] = a0; i1[s] = a1; g0[s] = m0; g1[s] = m1;
#pragma unroll
  for (int e = 0; e < E; ++e) {
    sel0[(size_t)s * (E * 2) + e * 2 + 0] = (e == a0 && m0 != 0.f) ? 1.f : 0.f;
    sel0[(size_t)s * (E * 2) + e * 2 + 1] = (e == a1 && m1 != 0.f) ? 1.f : 0.f;
  }
}

// balance_loss. Single block, deterministic.
__global__ void k_balance(const float* __restrict__ sel, const int* __restrict__ i0,
                          const int* __restrict__ i1, float* __restrict__ outb) {
  __shared__ double part[512];
  __shared__ float dpl[E];
  int t = threadIdx.x;
  int e = t & 15, r0 = t >> 4;
  double acc = 0.0;
  for (int s = r0; s < S; s += 32) acc += (double)sel[s * E + e];
  part[t] = acc;
  __syncthreads();
  for (int off = 256; off >= 16; off >>= 1) {
    if (t < off) part[t] += part[t + off];
    __syncthreads();
  }
  if (t < E) dpl[t] = (float)(part[t] / (double)S);
  __syncthreads();
  double acc2 = 0.0;
  for (int s = t; s < S; s += 512) acc2 += 0.5 * ((double)dpl[i0[s]] + (double)dpl[i1[s]]);
  part[t] = acc2;
  __syncthreads();
  for (int off = 256; off; off >>= 1) {
    if (t < off) part[t] += part[t + off];
    __syncthreads();
  }
  if (t == 0) outb[0] = (float)(part[0] / 256.0);
}

// expert_inputs partials: block = ((e*2+k)*4 + chunk)*NSEG + seg; scans 256 tokens.
__global__ void k_scatter_part(const float* __restrict__ x, const int* __restrict__ i0,
                               const int* __restrict__ i1, const float* __restrict__ g0,
                               const float* __restrict__ g1, float* __restrict__ part) {
  __shared__ int rsi[256];
  __shared__ float rsg[256];
  int b = blockIdx.x;
  int seg = b & (NSEG - 1);
  int rest = b >> 4;
  int chunk = rest & 3;
  int ek = rest >> 2;
  int k = ek & 1, e = ek >> 1;
  const int* route = k ? i1 : i0;
  const float* gg = k ? g1 : g0;
  int t = threadIdx.x;
  int d = chunk * 128 + t;
  int s0 = seg * (S / NSEG);
  rsi[t] = route[s0 + t];        rsi[t + 128] = route[s0 + t + 128];
  rsg[t] = gg[s0 + t];           rsg[t + 128] = gg[s0 + t + 128];
  __syncthreads();
  float acc = 0.f;
  for (int q = 0; q < 256; ++q) {
    if (rsi[q] == e && rsg[q] != 0.f) acc += x[(size_t)(s0 + q) * M + d];
  }
  part[(size_t)seg * (E * 2 * M) + (size_t)ek * M + d] = acc;
}

__global__ void k_scatter_red(const float* __restrict__ part, float* __restrict__ ei) {
  int idx = blockIdx.x * blockDim.x + threadIdx.x;
  float acc = 0.f;
#pragma unroll
  for (int sg = 0; sg < NSEG; ++sg) acc += part[(size_t)sg * (E * 2 * M) + idx];
  ei[idx] = acc;
}

// generic MLP layer: wave per (e,h) output neuron, both k rows at once
template <int DIN, int HOUT, bool RELU>
__global__ void k_layer(const float* __restrict__ in, const float* __restrict__ W,
                        const float* __restrict__ bias, float* __restrict__ out) {
  int w = (blockIdx.x * blockDim.x + threadIdx.x) >> 6;
  int lane = threadIdx.x & 63;
  if (w >= E * HOUT) return;
  int e = w / HOUT, h = w - e * HOUT;
  const float* wr = W + ((size_t)e * HOUT + h) * DIN;
  const float* in0 = in + (size_t)(e * 2 + 0) * DIN;
  const float* in1 = in + (size_t)(e * 2 + 1) * DIN;
  float a0 = 0.f, a1 = 0.f;
  for (int m = lane; m < DIN; m += 64) {
    float wv = wr[m];
    a0 += wv * in0[m];
    a1 += wv * in1[m];
  }
#pragma unroll
  for (int off = 32; off; off >>= 1) {
    a0 += __shfl_xor(a0, off);
    a1 += __shfl_xor(a1, off);
  }
  if (lane == 0) {
    float bb = bias[e * HOUT + h];
    float o0 = a0 + bb, o1 = a1 + bb;
    if (RELU) { o0 = fmaxf(o0, 0.f); o1 = fmaxf(o1, 0.f); }
    out[(size_t)(e * 2 + 0) * HOUT + h] = o0;
    out[(size_t)(e * 2 + 1) * HOUT + h] = o1;
  }
}

__global__ void k_output(const float* __restrict__ eo, const int* __restrict__ i0,
                         const int* __restrict__ i1, const float* __restrict__ g0,
                         const float* __restrict__ g1, float* __restrict__ out) {
  int idx = blockIdx.x * blockDim.x + threadIdx.x;
  if (idx >= S * CC) return;
  int s = idx >> 7, d = idx & (CC - 1);
  out[idx] = g0[s] * eo[(i0[s] * 2 + 0) * CC + d] + g1[s] * eo[(i1[s] * 2 + 1) * CC + d];
}

// T rows (source then target, zero pad) + row sq-norms
__global__ void k_buildT(const float* __restrict__ eo, const int* __restrict__ idx1,
                         const int* __restrict__ idx2, const int* __restrict__ i0,
                         const int* __restrict__ i1, const float* __restrict__ g0,
                         const float* __restrict__ g1, float* __restrict__ T,
                         float* __restrict__ sq, int ns, int n) {
  int r = blockIdx.x, d = threadIdx.x;
  float v = 0.f;
  if (r < ns)      { int t = idx1[r];      v = g0[t] * eo[(i0[t] * 2 + 0) * CC + d]; }
  else if (r < n)  { int t = idx2[r - ns]; v = g1[t] * eo[(i1[t] * 2 + 1) * CC + d]; }
  T[(size_t)r * CC + d] = v;
  __shared__ float red[128];
  red[d] = v * v;
  __syncthreads();
  for (int off = 64; off; off >>= 1) { if (d < off) red[d] += red[d + off]; __syncthreads(); }
  if (d == 0) sq[r] = red[0];
}

__global__ void k_colsum(const float* __restrict__ T, double* __restrict__ part, int n) {
  int d = threadIdx.x, b = blockIdx.x;
  int r0 = b * 128, r1 = min(r0 + 128, n);
  double acc = 0.0;
  for (int r = r0; r < r1; ++r) acc += (double)T[(size_t)r * CC + d];
  part[b * 128 + d] = acc;
}

__global__ void k_prep(const double* __restrict__ part, const float* __restrict__ sq,
                       float* __restrict__ cl, int n, int nblk) {
  __shared__ double red[128];
  __shared__ double csum2s;
  int d = threadIdx.x;
  double cs = 0.0;
  for (int b = 0; b < nblk; ++b) cs += part[b * 128 + d];
  red[d] = cs * cs;
  __syncthreads();
  for (int off = 64; off; off >>= 1) { if (d < off) red[d] += red[d + off]; __syncthreads(); }
  if (d == 0) csum2s = red[0];
  __syncthreads();
  double ss = 0.0;
  for (int r = d; r < n; r += 128) ss += (double)sq[r];
  red[d] = ss;
  __syncthreads();
  for (int off = 64; off; off >>= 1) { if (d < off) red[d] += red[d + off]; __syncthreads(); }
  if (d == 0) {
    double ssq = red[0];
    double nn = (double)n;
    double bwsum = 2.0 * nn * ssq - 2.0 * csum2s;
    double bw = bwsum / (nn * nn - nn) / 4.0;
#pragma unroll
    for (int l = 0; l < 5; ++l) cl[l] = (float)(1.0 / (bw * (double)(1 << l)));
  }
}

__device__ inline unsigned short bf16_rne(float f) {
  unsigned b = __float_as_uint(f);
  return (unsigned short)((b + 0x7FFFu + ((b >> 16) & 1u)) >> 16);
}

// MMD via split-bf16 MFMA: Gram = hi*hi + lo*hi + hi*lo (f32 accumulate),
// 128x128 tiles over the upper triangle, exp-squaring epilogue.
__global__ __launch_bounds__(256) void k_mmd(const float* __restrict__ T, const float* __restrict__ sq,
                      const float* __restrict__ cl, double* __restrict__ bsum,
                      int ns, int n, int nt) {
  // decode linear upper-tri index -> (bi, bj), bi<=bj
  int L = blockIdx.x;
  int bi = 0, rem = L;
  while (rem >= nt - bi) { rem -= nt - bi; ++bi; }
  int bj = bi + rem;

  __shared__ short plane[4][128 * 128];   // Ahi, Alo, Bhi, Blo (kg-XOR swizzled)
  __shared__ float sqa_s[128], sqb_s[128], sga_s[128], sgb_s[128];
  __shared__ float rsum[256];
  int tid = threadIdx.x;
  int lane = tid & 63, wid = tid >> 6;
  const int ib = bi * 128, jb = bj * 128;

  // stage both tiles: f32 -> (hi,lo) bf16 planes, swizzle kg' = kg ^ (row&15)
#pragma unroll
  for (int side = 0; side < 2; ++side) {
    int base = side ? jb : ib;
    short* ph = plane[side * 2 + 0];
    short* pl = plane[side * 2 + 1];
#pragma unroll
    for (int i = 0; i < 8; ++i) {
      int idx = tid + i * 256;          // 2048 kg-units
      int row = idx >> 4, kg = idx & 15;
      const float* src = T + (size_t)(base + row) * CC + kg * 8;
      float4 v0 = *(const float4*)src;
      float4 v1 = *(const float4*)(src + 4);
      float f[8] = {v0.x, v0.y, v0.z, v0.w, v1.x, v1.y, v1.z, v1.w};
      short8 h, l;
#pragma unroll
      for (int e2 = 0; e2 < 8; ++e2) {
        unsigned short hb = bf16_rne(f[e2]);
        float hf = __uint_as_float(((unsigned)hb) << 16);
        h[e2] = (short)hb;
        l[e2] = (short)bf16_rne(f[e2] - hf);
      }
      int sk = kg ^ (row & 15);
      *(short8*)&ph[row * 128 + sk * 8] = h;
      *(short8*)&pl[row * 128 + sk * 8] = l;
    }
  }
  if (tid < 128) {
    int i = ib + tid, j = jb + tid;
    sqa_s[tid] = sq[i];
    sqb_s[tid] = sq[j];
    sga_s[tid] = (i < ns) ? 1.f : (i < n ? -1.f : 0.f);
    sgb_s[tid] = (j < ns) ? 1.f : (j < n ? -1.f : 0.f);
  }
  __syncthreads();

  int wr = wid >> 1, wc = wid & 1;
  int rowoff = wr * 64, coloff = wc * 64;
  f32x16 acc[2][2];
#pragma unroll
  for (int a = 0; a < 2; ++a)
#pragma unroll
    for (int b = 0; b < 2; ++b) acc[a][b] = (f32x16)(0.f);

  int lrow = lane & 31, khalf = lane >> 5;
#pragma unroll
  for (int pass = 0; pass < 3; ++pass) {
    const short* Ap = plane[pass == 1 ? 1 : 0];
    const short* Bp = plane[pass == 2 ? 3 : 2];
#pragma unroll
    for (int ks = 0; ks < 8; ++ks) {
      int kg = ks * 2 + khalf;
      int ra0 = rowoff + lrow, ra1 = ra0 + 32;
      int rb0 = coloff + lrow, rb1 = rb0 + 32;
      short8 a0 = *(const short8*)&Ap[ra0 * 128 + (kg ^ (ra0 & 15)) * 8];
      short8 a1 = *(const short8*)&Ap[ra1 * 128 + (kg ^ (ra1 & 15)) * 8];
      short8 b0 = *(const short8*)&Bp[rb0 * 128 + (kg ^ (rb0 & 15)) * 8];
      short8 b1 = *(const short8*)&Bp[rb1 * 128 + (kg ^ (rb1 & 15)) * 8];
      acc[0][0] = __builtin_amdgcn_mfma_f32_32x32x16_bf16(a0, b0, acc[0][0], 0, 0, 0);
      acc[0][1] = __builtin_amdgcn_mfma_f32_32x32x16_bf16(a0, b1, acc[0][1], 0, 0, 0);
      acc[1][0] = __builtin_amdgcn_mfma_f32_32x32x16_bf16(a1, b0, acc[1][0], 0, 0, 0);
      acc[1][1] = __builtin_amdgcn_mfma_f32_32x32x16_bf16(a1, b1, acc[1][1], 0, 0, 0);
    }
  }

  // epilogue: d2 -> 1 exp + 4 squarings (scales are powers of 2), signed sum
  float c4v = cl[4];
  float tsum = 0.f;
#pragma unroll
  for (int rb = 0; rb < 2; ++rb) {
    float sqm[16], sgm[16];
#pragma unroll
    for (int r = 0; r < 16; ++r) {
      int m = rowoff + rb * 32 + ((r & 3) + 8 * (r >> 2) + 4 * khalf);
      sqm[r] = sqa_s[m];
      sgm[r] = sga_s[m];
    }
#pragma unroll
    for (int cb = 0; cb < 2; ++cb) {
      int nn = coloff + cb * 32 + lrow;
      float sqn = sqb_s[nn], sgn = sgb_s[nn];
      f32x16 A = acc[rb][cb];
#pragma unroll
      for (int r = 0; r < 16; ++r) {
        float d2 = sqm[r] + sqn - 2.f * A[r];
        float t = __expf(-d2 * c4v);
        float s5 = t;
        t = t * t; s5 += t;
        t = t * t; s5 += t;
        t = t * t; s5 += t;
        t = t * t; s5 += t;
        tsum += sgm[r] * sgn * s5;
      }
    }
  }
  rsum[tid] = tsum;
  __syncthreads();
  for (int off = 128; off; off >>= 1) {
    if (tid < off) rsum[tid] += rsum[tid + off];
    __syncthreads();
  }
  if (tid == 0) bsum[L] = (double)rsum[0] * ((bi == bj) ? 1.0 : 2.0);
}

__global__ void k_final(const double* __restrict__ bsum, int nb, int ns, float* __restrict__ outp) {
  __shared__ double red[256];
  int t = threadIdx.x;
  double acc = 0.0;
  for (int i = t; i < nb; i += 256) acc += bsum[i];
  red[t] = acc;
  __syncthreads();
  for (int off = 128; off; off >>= 1) { if (t < off) red[t] += red[t + off]; __syncthreads(); }
  if (t == 0) outp[0] = (float)(-red[0] / ((double)ns * (double)ns));
}

extern "C" void kernel_launch(void* const* d_in, const int* in_sizes, int n_in,
                              void* d_out, int out_size, void* d_ws, size_t ws_size,
                              hipStream_t stream) {
  const float* x  = (const float*)d_in[0];
  const float* noise = (const float*)d_in[1];
  const float* Wr = (const float*)d_in[2];
  const float* W1 = (const float*)d_in[3];
  const float* b1 = (const float*)d_in[4];
  const float* W2 = (const float*)d_in[5];
  const float* b2 = (const float*)d_in[6];
  const float* W3 = (const float*)d_in[7];
  const float* b3 = (const float*)d_in[8];
  const float* W4 = (const float*)d_in[9];
  const float* b4 = (const float*)d_in[10];
  const int* idx1 = (const int*)d_in[11];
  const int* idx2 = (const int*)d_in[12];
  int ns = in_sizes[11];
  int n = 2 * ns;
  int npad = (n + 127) & ~127;
  int nt = npad / 128;
  int ntri = nt * (nt + 1) / 2;
  int nblk = (n + 127) / 128;

  char* wp = (char*)d_ws;
  size_t off = 0;
  auto alloc = [&](size_t bytes) -> void* {
    void* p = wp + off;
    off += (bytes + 255) & ~(size_t)255;
    return p;
  };
  float* sel = (float*)alloc((size_t)S * E * 4);
  int*   i0  = (int*)alloc((size_t)S * 4);
  int*   i1  = (int*)alloc((size_t)S * 4);
  float* g0  = (float*)alloc((size_t)S * 4);
  float* g1  = (float*)alloc((size_t)S * 4);
  float* ei  = (float*)alloc((size_t)E * 2 * M * 4);
  float* eipart = (float*)alloc((size_t)NSEG * E * 2 * M * 4);
  float* h1  = (float*)alloc((size_t)E * 2 * H1 * 4);
  float* h2  = (float*)alloc((size_t)E * 2 * H2 * 4);
  float* h3  = (float*)alloc((size_t)E * 2 * H3 * 4);
  float* eo  = (float*)alloc((size_t)E * 2 * CC * 4);
  float* T   = (float*)alloc((size_t)npad * CC * 4);
  float* sq  = (float*)alloc((size_t)npad * 4);
  float* cl  = (float*)alloc(8 * 4);
  double* cspart = (double*)alloc((size_t)nblk * 128 * 8);
  double* bsum   = (double*)alloc((size_t)ntri * 8);
  (void)ws_size; (void)n_in; (void)out_size;

  float* out      = (float*)d_out;
  float* out_sel0 = out + (size_t)S * CC;
  float* out_bal  = out + (size_t)S * CC + (size_t)S * E * 2;
  float* out_dist = out_bal + 1;

  k_select<<<S / 4, 256, 0, stream>>>(x, noise, Wr, sel);
  k_top2<<<S / 256, 256, 0, stream>>>(sel, i0, i1, g0, g1, out_sel0);
  k_balance<<<1, 512, 0, stream>>>(sel, i0, i1, out_bal);
  k_scatter_part<<<E * 2 * 4 * NSEG, 128, 0, stream>>>(x, i0, i1, g0, g1, eipart);
  k_scatter_red<<<(E * 2 * M) / 256, 256, 0, stream>>>(eipart, ei);
  k_layer<M, H1, true><<<(E * H1 + 3) / 4, 256, 0, stream>>>(ei, W1, b1, h1);
  k_layer<H1, H2, true><<<(E * H2 + 3) / 4, 256, 0, stream>>>(h1, W2, b2, h2);
  k_layer<H2, H3, true><<<(E * H3 + 3) / 4, 256, 0, stream>>>(h2, W3, b3, h3);
  k_layer<H3, CC, false><<<(E * CC + 3) / 4, 256, 0, stream>>>(h3, W4, b4, eo);
  k_output<<<(S * CC) / 256, 256, 0, stream>>>(eo, i0, i1, g0, g1, out);
  k_buildT<<<npad, 128, 0, stream>>>(eo, idx1, idx2, i0, i1, g0, g1, T, sq, ns, n);
  k_colsum<<<nblk, 128, 0, stream>>>(T, cspart, n);
  k_prep<<<1, 128, 0, stream>>>(cspart, sq, cl, n, nblk);
  k_mmd<<<ntri, 256, 0, stream>>>(T, sq, cl, bsum, ns, n, nt);
  k_final<<<1, 256, 0, stream>>>(bsum, ntri, ns, out_dist);
}